// Round 1
// baseline (1015.006 us; speedup 1.0000x reference)
//
#include <hip/hip_runtime.h>
#include <math.h>

#define BATCH 8
#define SEQ 2048
#define DIM 128
#define TK 64
#define SCALE 0.08838834764831845f  // 1/sqrt(128)

// ---------------- vmean: partial sums over 256-row chunks ----------------
__global__ __launch_bounds__(256) void vmean_partial(const float* __restrict__ v,
                                                     float* __restrict__ part) {
    int blk = blockIdx.x;            // 64 blocks: b*8 + oct
    int b = blk >> 3, oct = blk & 7;
    int t = threadIdx.x;
    int d4 = t & 31, rg = t >> 5;    // d4: float4 col, rg: row group
    const float4* vb = (const float4*)(v + (size_t)b * SEQ * DIM);
    float4 acc = make_float4(0.f, 0.f, 0.f, 0.f);
    int base = oct * 256 + rg * 32;
    #pragma unroll 8
    for (int i = 0; i < 32; ++i) {
        float4 x = vb[(size_t)(base + i) * 32 + d4];
        acc.x += x.x; acc.y += x.y; acc.z += x.z; acc.w += x.w;
    }
    __shared__ float4 red[8][32];
    red[rg][d4] = acc;
    __syncthreads();
    if (t < 32) {
        float4 s = red[0][t];
        #pragma unroll
        for (int r = 1; r < 8; ++r) {
            float4 x = red[r][t];
            s.x += x.x; s.y += x.y; s.z += x.z; s.w += x.w;
        }
        ((float4*)part)[(size_t)blk * 32 + t] = s;
    }
}

__global__ __launch_bounds__(128) void vmean_combine(const float* __restrict__ part,
                                                     float* __restrict__ vmean) {
    int b = blockIdx.x, t = threadIdx.x;   // 8 blocks x 128 threads
    float s = 0.f;
    #pragma unroll
    for (int o = 0; o < 8; ++o) s += part[((size_t)b * 8 + o) * DIM + t];
    vmean[b * DIM + t] = s * (1.0f / SEQ);
}

// ---------------- main flash-attention kernel ----------------
// Block = 256 threads = 4 waves; wave owns 4 q-rows; 16 rows/block.
// Grid = 8 * 128 = 1024 blocks; blk&7 = batch (interleaved for balance).
__global__ __launch_bounds__(256) void attn_kernel(const float* __restrict__ q,
                                                   const float* __restrict__ k,
                                                   const float* __restrict__ v,
                                                   const int* __restrict__ lens,
                                                   const float* __restrict__ vmean,
                                                   float* __restrict__ out) {
    __shared__ float sK[TK * DIM];   // 32 KB, XOR-swizzled float4 slots
    __shared__ float sQ[16 * DIM];   // 8 KB

    int blk = blockIdx.x;
    int b = blk & 7;
    int qt = blk >> 3;               // 0..127
    int q0 = qt * 16;
    int len = lens[b];
    int t = threadIdx.x;
    int lane = t & 63;
    int wave = t >> 6;
    const size_t bo = (size_t)b * SEQ * DIM;

    float2 O[4];
    float m[4], l[4];
    #pragma unroll
    for (int r = 0; r < 4; ++r) { O[r] = make_float2(0.f, 0.f); m[r] = -INFINITY; l[r] = 0.f; }

    if (q0 < len) {
        // stage the 16 q rows
        const float4* q4 = (const float4*)(q + bo + (size_t)q0 * DIM);
        float4* sQ4 = (float4*)sQ;
        sQ4[t] = q4[t];
        sQ4[t + 256] = q4[t + 256];

        float4* sK4 = (float4*)sK;
        const float4* k4 = (const float4*)(k + bo);
        const float2* v2 = (const float2*)(v + bo);

        for (int t0 = 0; t0 < len; t0 += TK) {
            __syncthreads();   // protect previous tile reads; also fences sQ staging on iter 0... (need it before reads)
            #pragma unroll
            for (int i = 0; i < 8; ++i) {
                int f = i * 256 + t;
                int j = f >> 5, d4 = f & 31;
                sK4[j * 32 + (d4 ^ (j & 31))] = k4[(size_t)(t0 + j) * 32 + d4];
            }
            __syncthreads();

            int key = t0 + lane;
            bool kvalid = key < len;

            #pragma unroll
            for (int r = 0; r < 4; ++r) {
                int row = q0 + wave * 4 + r;        // wave-uniform
                if (row >= len) continue;           // no barriers inside: safe
                const float4* qrow = (const float4*)(sQ + (wave * 4 + r) * DIM);
                float s = 0.f;
                #pragma unroll 8
                for (int d4 = 0; d4 < 32; ++d4) {
                    float4 kk = sK4[lane * 32 + (d4 ^ (lane & 31))];
                    float4 qq = qrow[d4];
                    s += qq.x * kk.x + qq.y * kk.y + qq.z * kk.z + qq.w * kk.w;
                }
                s *= SCALE;
                float sv = kvalid ? s : -INFINITY;
                float mt = sv;
                #pragma unroll
                for (int off = 32; off; off >>= 1) mt = fmaxf(mt, __shfl_xor(mt, off));
                float mnew = fmaxf(m[r], mt);
                float p = kvalid ? __expf(s - mnew) : 0.f;
                float ps = p;
                #pragma unroll
                for (int off = 32; off; off >>= 1) ps += __shfl_xor(ps, off);
                float alpha = __expf(m[r] - mnew);  // exp(-inf)=0 on first tile
                m[r] = mnew;
                l[r] = l[r] * alpha + ps;
                O[r].x *= alpha; O[r].y *= alpha;
                #pragma unroll 16
                for (int j = 0; j < TK; ++j) {
                    float pj = __shfl(p, j);
                    float2 vv = v2[(size_t)(t0 + j) * 64 + lane];
                    O[r].x += pj * vv.x;
                    O[r].y += pj * vv.y;
                }
            }
        }
    }

    // epilogue: valid rows -> O/l, masked rows -> vmean (uniform softmax over all S)
    #pragma unroll
    for (int r = 0; r < 4; ++r) {
        int row = q0 + wave * 4 + r;
        float2* orow = (float2*)(out + bo + (size_t)row * DIM);
        if (row < len) {
            float inv = 1.f / l[r];
            orow[lane] = make_float2(O[r].x * inv, O[r].y * inv);
        } else {
            const float2* vm = (const float2*)(vmean + b * DIM);
            orow[lane] = vm[lane];
        }
    }
}

extern "C" void kernel_launch(void* const* d_in, const int* in_sizes, int n_in,
                              void* d_out, int out_size, void* d_ws, size_t ws_size,
                              hipStream_t stream) {
    const float* q = (const float*)d_in[0];
    const float* k = (const float*)d_in[1];
    const float* v = (const float*)d_in[2];
    const int* lens = (const int*)d_in[3];
    float* out = (float*)d_out;

    float* part = (float*)d_ws;                 // 64 * 128 floats = 32 KB
    float* vmean = part + 64 * DIM;             // 8 * 128 floats = 4 KB

    vmean_partial<<<dim3(64), dim3(256), 0, stream>>>(v, part);
    vmean_combine<<<dim3(8), dim3(128), 0, stream>>>(part, vmean);
    attn_kernel<<<dim3(1024), dim3(256), 0, stream>>>(q, k, v, lens, vmean, out);
}

// Round 2
// 159.729 us; speedup vs baseline: 6.3546x; 6.3546x over previous
//
#include <hip/hip_runtime.h>
#include <math.h>

#define BATCH 8
#define SEQ 2048
#define DIM 128
#define TK 64
#define SCALE 0.08838834764831845f  // 1/sqrt(128)
#define NEGINF (-1e30f)

typedef __attribute__((ext_vector_type(8))) short short8;
typedef __attribute__((ext_vector_type(4))) float floatx4;

// LDS row strides in bf16 units (chosen for min-conflict b128 frag reads, 16B alignment)
#define KSTR 136   // sK: 64 rows  x 136 -> byte stride 272 = 17*16
#define VSTR 72    // sVt: 128 rows x 72 -> byte stride 144 = 9*16
#define PSTR 72    // sP: per-wave 16 rows

__device__ __forceinline__ unsigned f2bf(float f) {  // RNE f32->bf16 bit pattern
    unsigned u = __float_as_uint(f);
    u += 0x7fffu + ((u >> 16) & 1u);
    return u >> 16;
}

// ---------------- vmean: mean of all SEQ V-rows per batch ----------------
__global__ __launch_bounds__(256) void vmean_partial(const float* __restrict__ v,
                                                     float* __restrict__ part) {
    int blk = blockIdx.x;            // 64 blocks: b*8 + oct
    int b = blk >> 3, oct = blk & 7;
    int t = threadIdx.x;
    int d4 = t & 31, rg = t >> 5;
    const float4* vb = (const float4*)(v + (size_t)b * SEQ * DIM);
    float4 acc = make_float4(0.f, 0.f, 0.f, 0.f);
    int base = oct * 256 + rg * 32;
    #pragma unroll 8
    for (int i = 0; i < 32; ++i) {
        float4 x = vb[(size_t)(base + i) * 32 + d4];
        acc.x += x.x; acc.y += x.y; acc.z += x.z; acc.w += x.w;
    }
    __shared__ float4 red[8][32];
    red[rg][d4] = acc;
    __syncthreads();
    if (t < 32) {
        float4 s = red[0][t];
        #pragma unroll
        for (int r = 1; r < 8; ++r) {
            float4 x = red[r][t];
            s.x += x.x; s.y += x.y; s.z += x.z; s.w += x.w;
        }
        ((float4*)part)[(size_t)blk * 32 + t] = s;
    }
}

__global__ __launch_bounds__(128) void vmean_combine(const float* __restrict__ part,
                                                     float* __restrict__ vmean) {
    int b = blockIdx.x, t = threadIdx.x;
    float s = 0.f;
    #pragma unroll
    for (int o = 0; o < 8; ++o) s += part[((size_t)b * 8 + o) * DIM + t];
    vmean[b * DIM + t] = s * (1.0f / SEQ);
}

// ---------------- MFMA flash attention ----------------
// Block = 256 threads = 4 waves. Wave w owns 16 q-rows; block Q-tile = 64 rows.
// Grid = 8 * 32 = 256 blocks; blk&7 = batch (interleaved for balance).
__global__ __launch_bounds__(256) void attn_mfma(const float* __restrict__ q,
                                                 const float* __restrict__ k,
                                                 const float* __restrict__ v,
                                                 const int* __restrict__ lens,
                                                 const float* __restrict__ vmean,
                                                 float* __restrict__ out) {
    __shared__ unsigned short sK[64 * KSTR];       // 17408 B, row-major [key][d]
    __shared__ unsigned short sVt[DIM * VSTR];     // 18432 B, transposed [d][key]
    __shared__ unsigned short sP[4 * 16 * PSTR];   //  9216 B, per-wave P tiles

    int blk = blockIdx.x;
    int b = blk & 7;
    int qt = blk >> 3;               // 0..31
    int q0 = qt * 64;
    int len = lens[b];
    int t = threadIdx.x;
    int lane = t & 63;
    int w = t >> 6;
    int l16 = lane & 15;
    int quad = lane >> 4;
    const size_t bo = (size_t)b * SEQ * DIM;

    floatx4 O[8];                    // O C-frags: rows quad*4+r, cols dt*16+l16
    float m_r[4], l_r[4];
    #pragma unroll
    for (int dt = 0; dt < 8; ++dt) O[dt] = (floatx4){0.f, 0.f, 0.f, 0.f};
    #pragma unroll
    for (int r = 0; r < 4; ++r) { m_r[r] = NEGINF; l_r[r] = 0.f; }

    int rowbase = q0 + w * 16;
    bool blk_active = q0 < len;

    if (blk_active) {
        // ---- Q A-frags (persist in registers): m=l16 (row), k=quad*8+jj (d) ----
        short8 Qf[4];
        {
            const float* qrow = q + bo + (size_t)(rowbase + l16) * DIM + quad * 8;
            #pragma unroll
            for (int ds = 0; ds < 4; ++ds) {
                float4 x0 = *(const float4*)(qrow + ds * 32);
                float4 x1 = *(const float4*)(qrow + ds * 32 + 4);
                union { short8 s8; unsigned u[4]; } uu;
                uu.u[0] = f2bf(x0.x) | (f2bf(x0.y) << 16);
                uu.u[1] = f2bf(x0.z) | (f2bf(x0.w) << 16);
                uu.u[2] = f2bf(x1.x) | (f2bf(x1.y) << 16);
                uu.u[3] = f2bf(x1.z) | (f2bf(x1.w) << 16);
                Qf[ds] = uu.s8;
            }
        }

        for (int t0 = 0; t0 < len; t0 += TK) {
            __syncthreads();   // protect previous tile's LDS reads

            // ---- stage K tile: [key][d] bf16, coalesced float4 loads ----
            {
                int key = t >> 5, d4 = t & 31;
                const float4* kbase = (const float4*)(k + bo);
                #pragma unroll
                for (int i = 0; i < 8; ++i) {
                    int kk = key + i * 8;
                    int kg = t0 + kk; kg = kg < SEQ ? kg : SEQ - 1;  // clamp (masked anyway)
                    float4 x = kbase[(size_t)kg * 32 + d4];
                    uint2 pk;
                    pk.x = f2bf(x.x) | (f2bf(x.y) << 16);
                    pk.y = f2bf(x.z) | (f2bf(x.w) << 16);
                    *(uint2*)&sK[kk * KSTR + d4 * 4] = pk;
                }
            }
            // ---- stage V^T tile: [d][key] bf16; scalar loads, packed row writes ----
            {
                int d = t & 127;
                int kb = (t >> 7) * 4;   // 0 or 4
                const float* vbase = v + bo + d;
                #pragma unroll
                for (int p = 0; p < 8; ++p) {
                    int kk = kb + p * 8;
                    int g0 = t0 + kk;
                    int c0 = g0 + 0 < SEQ ? g0 + 0 : SEQ - 1;
                    int c1 = g0 + 1 < SEQ ? g0 + 1 : SEQ - 1;
                    int c2 = g0 + 2 < SEQ ? g0 + 2 : SEQ - 1;
                    int c3 = g0 + 3 < SEQ ? g0 + 3 : SEQ - 1;
                    float x0 = vbase[(size_t)c0 * DIM];
                    float x1 = vbase[(size_t)c1 * DIM];
                    float x2 = vbase[(size_t)c2 * DIM];
                    float x3 = vbase[(size_t)c3 * DIM];
                    uint2 pk;
                    pk.x = f2bf(x0) | (f2bf(x1) << 16);
                    pk.y = f2bf(x2) | (f2bf(x3) << 16);
                    *(uint2*)&sVt[d * VSTR + kk] = pk;
                }
            }
            __syncthreads();

            if (rowbase < len) {   // wave-uniform; no barriers inside
                // ---- QK^T: S[nt] = Q . K^T, 16 MFMAs ----
                floatx4 S[4];
                #pragma unroll
                for (int nt = 0; nt < 4; ++nt) {
                    floatx4 acc = (floatx4){0.f, 0.f, 0.f, 0.f};
                    const unsigned short* kr = &sK[(nt * 16 + l16) * KSTR + quad * 8];
                    #pragma unroll
                    for (int ds = 0; ds < 4; ++ds) {
                        short8 Kf = *(const short8*)(kr + ds * 32);
                        acc = __builtin_amdgcn_mfma_f32_16x16x32_bf16(Qf[ds], Kf, acc, 0, 0, 0);
                    }
                    S[nt] = acc;
                }

                // ---- online softmax on C-layout frags ----
                int keybase = t0 + l16;
                float mt[4];
                #pragma unroll
                for (int r = 0; r < 4; ++r) mt[r] = m_r[r];
                #pragma unroll
                for (int nt = 0; nt < 4; ++nt) {
                    bool valid = (keybase + nt * 16) < len;
                    #pragma unroll
                    for (int r = 0; r < 4; ++r) {
                        float s = valid ? S[nt][r] * SCALE : NEGINF;
                        S[nt][r] = s;
                        mt[r] = fmaxf(mt[r], s);
                    }
                }
                #pragma unroll
                for (int r = 0; r < 4; ++r) {
                    #pragma unroll
                    for (int off = 1; off <= 8; off <<= 1)
                        mt[r] = fmaxf(mt[r], __shfl_xor(mt[r], off));
                }
                float alpha[4], ps[4];
                #pragma unroll
                for (int r = 0; r < 4; ++r) {
                    alpha[r] = __expf(m_r[r] - mt[r]);
                    m_r[r] = mt[r];
                    ps[r] = 0.f;
                }
                #pragma unroll
                for (int nt = 0; nt < 4; ++nt) {
                    #pragma unroll
                    for (int r = 0; r < 4; ++r) {
                        float p = __expf(S[nt][r] - m_r[r]);  // masked -> exp(-1e30)=0
                        S[nt][r] = p;
                        ps[r] += p;
                    }
                }
                #pragma unroll
                for (int r = 0; r < 4; ++r) {
                    #pragma unroll
                    for (int off = 1; off <= 8; off <<= 1)
                        ps[r] += __shfl_xor(ps[r], off);
                    l_r[r] = l_r[r] * alpha[r] + ps[r];
                }
                #pragma unroll
                for (int dt = 0; dt < 8; ++dt) {
                    #pragma unroll
                    for (int r = 0; r < 4; ++r) O[dt][r] *= alpha[r];
                }

                // ---- P: C-layout -> LDS -> A-layout (m120 pattern), then PV ----
                unsigned short* myP = &sP[w * 16 * PSTR];
                #pragma unroll
                for (int nt = 0; nt < 4; ++nt) {
                    #pragma unroll
                    for (int r = 0; r < 4; ++r)
                        myP[(quad * 4 + r) * PSTR + nt * 16 + l16] =
                            (unsigned short)f2bf(S[nt][r]);
                }
                // wave-local RAW on sP: compiler orders DS ops + lgkmcnt (same array)
                #pragma unroll
                for (int js = 0; js < 2; ++js) {
                    short8 Pf = *(const short8*)(&myP[l16 * PSTR + js * 32 + quad * 8]);
                    #pragma unroll
                    for (int dt = 0; dt < 8; ++dt) {
                        short8 Vf = *(const short8*)(&sVt[(dt * 16 + l16) * VSTR + js * 32 + quad * 8]);
                        O[dt] = __builtin_amdgcn_mfma_f32_16x16x32_bf16(Pf, Vf, O[dt], 0, 0, 0);
                    }
                }
            }
        }
    }

    // ---- epilogue: valid rows -> O/l; masked rows -> vmean ----
    #pragma unroll
    for (int r = 0; r < 4; ++r) {
        int row = rowbase + quad * 4 + r;
        float* orow = out + bo + (size_t)row * DIM + l16;
        if (row < len) {
            float inv = 1.f / l_r[r];
            #pragma unroll
            for (int dt = 0; dt < 8; ++dt) orow[dt * 16] = O[dt][r] * inv;
        } else {
            const float* vm = vmean + b * DIM + l16;
            #pragma unroll
            for (int dt = 0; dt < 8; ++dt) orow[dt * 16] = vm[dt * 16];
        }
    }
}

extern "C" void kernel_launch(void* const* d_in, const int* in_sizes, int n_in,
                              void* d_out, int out_size, void* d_ws, size_t ws_size,
                              hipStream_t stream) {
    const float* q = (const float*)d_in[0];
    const float* k = (const float*)d_in[1];
    const float* v = (const float*)d_in[2];
    const int* lens = (const int*)d_in[3];
    float* out = (float*)d_out;

    float* part = (float*)d_ws;                 // 64*128 floats
    float* vmean = part + 64 * DIM;             // 8*128 floats

    vmean_partial<<<dim3(64), dim3(256), 0, stream>>>(v, part);
    vmean_combine<<<dim3(8), dim3(128), 0, stream>>>(part, vmean);
    attn_mfma<<<dim3(256), dim3(256), 0, stream>>>(q, k, v, lens, vmean, out);
}